// Round 9
// baseline (511.784 us; speedup 1.0000x reference)
//
#include <hip/hip_runtime.h>

#define N_NODES 100000
#define N_EDGES 3200000
#define F_IN    1433
#define HID     16
#define N_CLS   7
#define CAP     96                                   // ELL capacity; Poisson(32) tail @96 ~ 1e-18
#define NWINT   48                                   // total K windows of 32 (K padded to 1536)
#define NWIN    12                                   // windows per wave (4 waves)
#define GB1     (N_NODES / 16)                       // 6250 gemm tiles of 16 rows (exact)
#define EB      (N_EDGES / 4 / 256)                  // 3125 edge-fill blocks (int4 per thread)
#define ROWBLKS ((N_NODES + 255) / 256)              // 391

typedef __attribute__((ext_vector_type(8))) short short8v;
typedef __attribute__((ext_vector_type(4))) float float4v;

__device__ __forceinline__ unsigned short f2bf(float f) {
    unsigned u = __float_as_uint(f);
    u += 0x7fffu + ((u >> 16) & 1u);                 // RNE
    return (unsigned short)(u >> 16);
}

// ---------------- prep: pre-swizzled bf16 W1 fragments ----------------
// w1f[(w*64+l)*8 + i] = bf16(W1[k][col]), k = w*32 + (l>>4)*8 + i, col = l&15,
// zero-padded past F_IN. 48KB total, L2-resident, broadcast to all gemm waves;
// each wave then fetches its B-frag with ONE dwordx4 per window.

__global__ void prep_w1_kernel(const float* __restrict__ W1, short* __restrict__ w1f) {
    int w = blockIdx.x;
    int l = threadIdx.x;
    int col = l & 15;
    int kb = w * 32 + (l >> 4) * 8;
    short8v f;
#pragma unroll
    for (int i = 0; i < 8; ++i) {
        int k = kb + i;
        float v = (k < F_IN) ? W1[k * HID + col] : 0.f;
        f[i] = (short)f2bf(v);
    }
    *(short8v*)(w1f + ((size_t)w * 64 + l) * 8) = f;
}

// ---------------- fat kernel: ELL fill (first) ++ gemm1 tiles ----------------
// Blocks [0, EB): single-pass ELL build — scheduled FIRST so the 3.2M-atomic
// scatter overlaps under the BW-bound gemm. Blocks [EB, EB+GB1): t1 = x @ W1
// via MFMA bf16 (R6/R7-verified fragment maps), B-frags streamed from w1f.

__global__ __launch_bounds__(256) void fat1_kernel(const float* __restrict__ x,
                                                   const short* __restrict__ w1f,
                                                   float* __restrict__ t1,
                                                   const int* __restrict__ src,
                                                   const int* __restrict__ dst,
                                                   int* __restrict__ cur,
                                                   int* __restrict__ ell) {
    const int bid = blockIdx.x;
    if (bid < EB) {
        // ---- ELL fill path ----
        int i = bid * 256 + threadIdx.x;
        if (i < N_EDGES / 4) {
            int4 s4 = ((const int4*)src)[i];
            int4 d4 = ((const int4*)dst)[i];
            int p;
            p = atomicAdd(&cur[d4.x], 1); if (p < CAP) ell[(size_t)d4.x * CAP + p] = s4.x;
            p = atomicAdd(&cur[d4.y], 1); if (p < CAP) ell[(size_t)d4.y * CAP + p] = s4.y;
            p = atomicAdd(&cur[d4.z], 1); if (p < CAP) ell[(size_t)d4.z * CAP + p] = s4.z;
            p = atomicAdd(&cur[d4.w], 1); if (p < CAP) ell[(size_t)d4.w * CAP + p] = s4.w;
        }
        return;
    }
    // ---- gemm1 path ----
    __shared__ float red[4][256];
    const int tid = threadIdx.x;
    const int s = tid >> 6;                // wave
    const int l = tid & 63;                // lane
    const int R0 = (bid - EB) * 16;
    const int g = l >> 4;                  // k-group
    const int c = l & 15;                  // A row / B col
    const int row = R0 + c;
    const float* __restrict__ xp = x + (size_t)row * F_IN + g * 8;
    const short* __restrict__ wfp = w1f + ((size_t)(s * NWIN) * 64 + l) * 8;

    float4v acc = {0.f, 0.f, 0.f, 0.f};
#pragma unroll
    for (int wl = 0; wl < NWIN; ++wl) {
        // B fragment: one dwordx4 from L2-resident w1f
        short8v bf = *(const short8v*)(wfp + (size_t)wl * 64 * 8);
        int kw = (s * NWIN + wl) * 32;
        float v[8];
        if (kw + 32 <= F_IN) {             // full window (wave-uniform)
#pragma unroll
            for (int i = 0; i < 8; ++i) v[i] = xp[kw + i];
        } else if (kw < F_IN) {            // partial window (wi==44)
#pragma unroll
            for (int i = 0; i < 8; ++i) {
                int k = kw + g * 8 + i;
                v[i] = (k < F_IN) ? x[(size_t)row * F_IN + k] : 0.f;
            }
        } else {                           // fully OOB (wi>=45): skip
            continue;
        }
        short8v af;
#pragma unroll
        for (int i = 0; i < 8; ++i) af[i] = (short)f2bf(v[i]);
        acc = __builtin_amdgcn_mfma_f32_16x16x32_bf16(af, bf, acc, 0, 0, 0);
    }

    // cross-wave K reduction (D map: col=l&15, row=4*(l>>4)+j — verified)
#pragma unroll
    for (int j = 0; j < 4; ++j) red[s][l * 4 + j] = acc[j];
    __syncthreads();
    {
        int r = tid >> 4, cc = tid & 15;
        int idx = ((r >> 2) * 16 + cc) * 4 + (r & 3);
        float v = red[0][idx] + red[1][idx] + red[2][idx] + red[3][idx];
        t1[(long)(R0 + r) * HID + cc] = v;
    }
}

// h = relu(gather-sum(t1) + t1 + b1); 4 lanes per node, float4 gathers
__global__ void agg1_kernel(const float* __restrict__ t1, const int* __restrict__ cur,
                            const int* __restrict__ ell, const float* __restrict__ b1,
                            float* __restrict__ h) {
    int tid = blockIdx.x * blockDim.x + threadIdx.x;
    if (tid >= N_NODES * 4) return;
    int node = tid >> 2;
    int q = tid & 3;
    int d = cur[node]; if (d > CAP) d = CAP;
    const int* el = ell + (size_t)node * CAP;
    float4 a = *(const float4*)(t1 + ((size_t)node * 16 + q * 4));
    float4 b = *(const float4*)(b1 + q * 4);
    a.x += b.x; a.y += b.y; a.z += b.z; a.w += b.w;
    for (int e = 0; e < d; ++e) {
        int s = el[e];
        float4 v = *(const float4*)(t1 + ((size_t)s * 16 + q * 4));
        a.x += v.x; a.y += v.y; a.z += v.z; a.w += v.w;
    }
    float4 r = {fmaxf(a.x, 0.f), fmaxf(a.y, 0.f), fmaxf(a.z, 0.f), fmaxf(a.w, 0.f)};
    *(float4*)(h + ((size_t)node * 16 + q * 4)) = r;
}

// ---------------- layer 2 (t2 padded to stride 8) ----------------

__global__ void gemm2_kernel(const float* __restrict__ h, const float* __restrict__ W2,
                             float* __restrict__ t2p) {
    int node = blockIdx.x * blockDim.x + threadIdx.x;
    if (node >= N_NODES) return;
    const float4* hr = (const float4*)(h + (size_t)node * HID);
    float hv[HID];
    ((float4*)hv)[0] = hr[0];
    ((float4*)hv)[1] = hr[1];
    ((float4*)hv)[2] = hr[2];
    ((float4*)hv)[3] = hr[3];
    float o8[8];
#pragma unroll
    for (int cNum = 0; cNum < N_CLS; ++cNum) {
        float a = 0.f;
#pragma unroll
        for (int j = 0; j < HID; ++j) a = fmaf(hv[j], W2[j * N_CLS + cNum], a);
        o8[cNum] = a;
    }
    o8[7] = 0.f;
    float4* op = (float4*)(t2p + (size_t)node * 8);
    op[0] = ((float4*)o8)[0];
    op[1] = ((float4*)o8)[1];
}

// out = gather-sum(t2) + t2 + b2; 2 lanes per node, float4 gathers
__global__ void agg2_kernel(const float* __restrict__ t2p, const int* __restrict__ cur,
                            const int* __restrict__ ell, const float* __restrict__ b2,
                            float* __restrict__ out) {
    int tid = blockIdx.x * blockDim.x + threadIdx.x;
    if (tid >= N_NODES * 2) return;
    int node = tid >> 1;
    int q = tid & 1;
    int d = cur[node]; if (d > CAP) d = CAP;
    const int* el = ell + (size_t)node * CAP;
    float4 a = *(const float4*)(t2p + ((size_t)node * 8 + q * 4));
    if (q == 0) {
        a.x += b2[0]; a.y += b2[1]; a.z += b2[2]; a.w += b2[3];
    } else {
        a.x += b2[4]; a.y += b2[5]; a.z += b2[6];
    }
    for (int e = 0; e < d; ++e) {
        int s = el[e];
        float4 v = *(const float4*)(t2p + ((size_t)s * 8 + q * 4));
        a.x += v.x; a.y += v.y; a.z += v.z; a.w += v.w;
    }
    float* op = out + (size_t)node * 7 + q * 4;
    op[0] = a.x; op[1] = a.y; op[2] = a.z;
    if (q == 0) op[3] = a.w;
}

// ---------------- launch ----------------

extern "C" void kernel_launch(void* const* d_in, const int* in_sizes, int n_in,
                              void* d_out, int out_size, void* d_ws, size_t ws_size,
                              hipStream_t stream) {
    const float* x  = (const float*)d_in[0];
    const int*   ei = (const int*)d_in[1];
    const float* W1 = (const float*)d_in[2];
    const float* b1 = (const float*)d_in[3];
    const float* W2 = (const float*)d_in[4];
    const float* b2 = (const float*)d_in[5];
    const int* src = ei;
    const int* dst = ei + N_EDGES;
    float* out = (float*)d_out;

    char* w = (char*)d_ws;
    float* t1  = (float*)w;  w += (size_t)N_NODES * HID * sizeof(float);
    float* h   = (float*)w;  w += (size_t)N_NODES * HID * sizeof(float);
    float* t2p = (float*)w;  w += (size_t)N_NODES * 8 * sizeof(float);
    int* cur   = (int*)w;    w += (size_t)N_NODES * sizeof(int);
    short* w1f = (short*)w;  w += (size_t)NWINT * 64 * 8 * sizeof(short);
    int* ell   = (int*)w;    w += (size_t)N_NODES * CAP * sizeof(int);

    hipMemsetAsync(cur, 0, (size_t)N_NODES * sizeof(int), stream);
    prep_w1_kernel<<<NWINT, 64, 0, stream>>>(W1, w1f);

    // ELL fill (first) ++ gemm1 (overlapped in one launch)
    fat1_kernel<<<EB + GB1, 256, 0, stream>>>(x, w1f, t1, src, dst, cur, ell);

    agg1_kernel<<<(N_NODES * 4 + 255) / 256, 256, 0, stream>>>(t1, cur, ell, b1, h);
    gemm2_kernel<<<ROWBLKS, 256, 0, stream>>>(h, W2, t2p);
    agg2_kernel<<<(N_NODES * 2 + 255) / 256, 256, 0, stream>>>(t2p, cur, ell, b2, out);
}